// Round 11
// baseline (52.728 us; speedup 1.0000x reference)
//
#include <hip/hip_runtime.h>
#include <math.h>
#include <stdint.h>

#define NTOK 8192
#define HID  4096
#define NEXP 64
#define TOPK 8

typedef float    f32x4 __attribute__((ext_vector_type(4)));
typedef _Float16 f16x8 __attribute__((ext_vector_type(8)));

// ws layout:
//   [0, 1MB)   : wq — W packed as MFMA B-fragments, f16 hi/lo, x2048 scale.
//                f16x8 entry index: gs*512 + E*128 + bank*64 + l
//                (gs = k-step 0..127 [32 k each], E = expert-tile 0..3,
//                 bank 0=hi 1=lo, l = lane). Element: expert e = E*16+(l&15),
//                 k = gs*32 + (l>>4)*8 + j, j=0..7.  -> every B load in k1 is
//                 64 lanes x 16 B CONTIGUOUS (1 KB, perfectly coalesced, L2-hot).
//   [1MB, 5MB) : lgp — logit partials [2][NTOK][64] f32 (x2048 scale)

__device__ __forceinline__ void cvt_hilo(f32x4 a, f32x4 b, f16x8& hi, f16x8& lo)
{
    float x[8] = {a.x, a.y, a.z, a.w, b.x, b.y, b.z, b.w};
#pragma unroll
    for (int j = 0; j < 8; ++j) {
        const _Float16 h = (_Float16)x[j];
        hi[j] = h;
        lo[j] = (_Float16)(x[j] - (float)h);
    }
}

// ---------------------------------------------------------------------
// k0: W fp32 -> packed B-fragments (x2048). 128 blocks x 256 thr.
// ---------------------------------------------------------------------
__global__ __launch_bounds__(256)
void k0_pack(const float* __restrict__ W, f16x8* __restrict__ wq)
{
    const int gidx = blockIdx.x * 256 + threadIdx.x;   // 0..32767
    const int s = gidx >> 8;            // k-step 0..127
    const int E = (gidx >> 6) & 3;      // expert tile
    const int l = gidx & 63;            // lane
    const int e = E * 16 + (l & 15);
    const int k = s * 32 + ((l >> 4) << 3);

    const float* src = W + (size_t)e * HID + k;
    const f32x4 w0 = *(const f32x4*)src;
    const f32x4 w1 = *(const f32x4*)(src + 4);
    f16x8 hi, lo;
    cvt_hilo(w0 * 2048.0f, w1 * 2048.0f, hi, lo);

    wq[s * 512 + E * 128 + l]      = hi;   // bank 0
    wq[s * 512 + E * 128 + 64 + l] = lo;   // bank 1
}

// ---------------------------------------------------------------------
// k1: partial logits (x2048), barrier-free streaming MFMA.
// grid = 1024 (tg = b>>1: 16 tokens; m = b&1: k-half) x 256 thr (4 waves).
// Wave w: k-slice m*2048 + w*512, 16 fully-unrolled steps of 32 k:
//   A: 2 f32x4 from HBM (depth-2 named ring), in-reg hi/lo split
//   B: 8 f16x8 from L2 (depth-2 named ring), pre-packed fragments
//   12 MFMA: accH (hi*hi) + accC (hi*lo then lo*hi, merged correction bank)
// No LDS, no barriers in the loop. One LDS reduce at the end (4 k-slices).
// ---------------------------------------------------------------------
#define ALD(S, GS) do { const float* _p = ha + (GS) * 32;                     \
    A##S##0 = *(const f32x4*)_p; A##S##1 = *(const f32x4*)(_p + 4); } while (0)

#define BLD(S, GS) do { const f16x8* _q = bq + (GS) * 512;                    \
    Bh##S##0 = _q[l];       Bl##S##0 = _q[64 + l];                            \
    Bh##S##1 = _q[128 + l]; Bl##S##1 = _q[192 + l];                           \
    Bh##S##2 = _q[256 + l]; Bl##S##2 = _q[320 + l];                           \
    Bh##S##3 = _q[384 + l]; Bl##S##3 = _q[448 + l]; } while (0)

#define CSTEP(S) do { f16x8 _ah, _al; cvt_hilo(A##S##0, A##S##1, _ah, _al);   \
    acH0 = __builtin_amdgcn_mfma_f32_16x16x32_f16(_ah, Bh##S##0, acH0, 0, 0, 0); \
    acH1 = __builtin_amdgcn_mfma_f32_16x16x32_f16(_ah, Bh##S##1, acH1, 0, 0, 0); \
    acH2 = __builtin_amdgcn_mfma_f32_16x16x32_f16(_ah, Bh##S##2, acH2, 0, 0, 0); \
    acH3 = __builtin_amdgcn_mfma_f32_16x16x32_f16(_ah, Bh##S##3, acH3, 0, 0, 0); \
    acC0 = __builtin_amdgcn_mfma_f32_16x16x32_f16(_ah, Bl##S##0, acC0, 0, 0, 0); \
    acC1 = __builtin_amdgcn_mfma_f32_16x16x32_f16(_ah, Bl##S##1, acC1, 0, 0, 0); \
    acC2 = __builtin_amdgcn_mfma_f32_16x16x32_f16(_ah, Bl##S##2, acC2, 0, 0, 0); \
    acC3 = __builtin_amdgcn_mfma_f32_16x16x32_f16(_ah, Bl##S##3, acC3, 0, 0, 0); \
    acC0 = __builtin_amdgcn_mfma_f32_16x16x32_f16(_al, Bh##S##0, acC0, 0, 0, 0); \
    acC1 = __builtin_amdgcn_mfma_f32_16x16x32_f16(_al, Bh##S##1, acC1, 0, 0, 0); \
    acC2 = __builtin_amdgcn_mfma_f32_16x16x32_f16(_al, Bh##S##2, acC2, 0, 0, 0); \
    acC3 = __builtin_amdgcn_mfma_f32_16x16x32_f16(_al, Bh##S##3, acC3, 0, 0, 0); \
} while (0)

#define KPAIR(N2) do { CSTEP(a); ALD(a, N2); BLD(a, N2);                      \
                       CSTEP(b); ALD(b, (N2) + 1); BLD(b, (N2) + 1); } while (0)

__global__ __launch_bounds__(256, 3)
void k1_logits(const float* __restrict__ Hm, const f16x8* __restrict__ wq,
               float* __restrict__ lgp)
{
    __shared__ float LB[4][1024];       // 16 KB: [wave][tok16 * 64 exp]

    const int tid  = threadIdx.x;
    const int w    = tid >> 6;
    const int l    = tid & 63;
    const int tg   = blockIdx.x >> 1;
    const int m    = blockIdx.x & 1;
    const int tok0 = tg * 16;
    const int kb   = m * 2048 + w * 512;        // wave's k base (floats)
    const int gs0  = kb >> 5;                   // wave's global k-step base

    const float* ha = Hm + (size_t)(tok0 + (l & 15)) * HID + kb + ((l >> 4) << 3);
    const f16x8* bq = wq + (size_t)gs0 * 512;

    f32x4 acH0 = (f32x4)(0.f), acH1 = (f32x4)(0.f), acH2 = (f32x4)(0.f), acH3 = (f32x4)(0.f);
    f32x4 acC0 = (f32x4)(0.f), acC1 = (f32x4)(0.f), acC2 = (f32x4)(0.f), acC3 = (f32x4)(0.f);

    f32x4 Aa0, Aa1, Ab0, Ab1;
    f16x8 Bha0, Bha1, Bha2, Bha3, Bla0, Bla1, Bla2, Bla3;
    f16x8 Bhb0, Bhb1, Bhb2, Bhb3, Blb0, Blb1, Blb2, Blb3;

    ALD(a, 0); BLD(a, 0);
    ALD(b, 1); BLD(b, 1);

    KPAIR(2);  KPAIR(4);  KPAIR(6);  KPAIR(8);
    KPAIR(10); KPAIR(12); KPAIR(14);
    CSTEP(a);  CSTEP(b);                // steps 14,15 (no further loads)

    // merge correction bank; C/D: col = l&15 (expert-in-tile), row = (l>>4)*4 + r (token)
    {
        const f32x4 v0 = acH0 + acC0, v1 = acH1 + acC1,
                    v2 = acH2 + acC2, v3 = acH3 + acC3;
#pragma unroll
        for (int r = 0; r < 4; ++r) {
            const int trow = ((l >> 4) << 2) + r;
            LB[w][trow * 64 +  0 + (l & 15)] = v0[r];
            LB[w][trow * 64 + 16 + (l & 15)] = v1[r];
            LB[w][trow * 64 + 32 + (l & 15)] = v2[r];
            LB[w][trow * 64 + 48 + (l & 15)] = v3[r];
        }
    }
    __syncthreads();

    // fixed-order 4-slice reduce -> lgp[m][tok0..tok0+15][0..63]
    {
        const f32x4* L0 = (const f32x4*)&LB[0][0];
        const f32x4* L1 = (const f32x4*)&LB[1][0];
        const f32x4* L2 = (const f32x4*)&LB[2][0];
        const f32x4* L3 = (const f32x4*)&LB[3][0];
        f32x4* o = (f32x4*)(lgp + ((size_t)m * NTOK + tok0) * 64);
        o[tid] = (L0[tid] + L1[tid]) + (L2[tid] + L3[tid]);
    }
}

// ---------------------------------------------------------------------
// k2: fixed-order 2-slice reduce + softmax + top-8 rank-count.
// 2048 blocks x 256 thr; 1 token per wave (proven form).
// ---------------------------------------------------------------------
__global__ __launch_bounds__(256)
void k2_finish(const float* __restrict__ lgp, float* __restrict__ out)
{
    __shared__ __align__(16) float sc[4][64];
    const int tid  = threadIdx.x;
    const int wave = tid >> 6;
    const int lane = tid & 63;
    float* outw = out;
    float* outi = out + (size_t)NTOK * TOPK;

    const int tok = blockIdx.x * 4 + wave;
    const float* p = lgp + (size_t)tok * 64 + lane;
    const float lgv = (p[0] + p[(size_t)NTOK * 64]) * (1.0f / 2048.0f);

    float mx = lgv;
#pragma unroll
    for (int off = 32; off; off >>= 1) mx = fmaxf(mx, __shfl_xor(mx, off));
    const float pv = expf(lgv - mx);
    float ss = pv;
#pragma unroll
    for (int off = 32; off; off >>= 1) ss += __shfl_xor(ss, off);
    ss = __shfl(ss, 0);                 // identical denominator on all lanes
    const float sval = pv / ss;

    sc[wave][lane] = sval;
    __syncthreads();

    int rank = 0;
#pragma unroll
    for (int j4 = 0; j4 < 16; ++j4) {
        const f32x4 v = *(const f32x4*)&sc[wave][j4 * 4];
#pragma unroll
        for (int u = 0; u < 4; ++u) {
            const int j = j4 * 4 + u;
            rank += (v[u] > sval || (v[u] == sval && j < lane)) ? 1 : 0;
        }
    }
    if (rank < TOPK) {
        outw[(size_t)tok * TOPK + rank] = sval;
        outi[(size_t)tok * TOPK + rank] = (float)lane;
    }
}

extern "C" void kernel_launch(void* const* d_in, const int* in_sizes, int n_in,
                              void* d_out, int out_size, void* d_ws, size_t ws_size,
                              hipStream_t stream) {
    (void)in_sizes; (void)n_in; (void)out_size; (void)ws_size;
    const float* h = (const float*)d_in[0];   // [8192, 4096] fp32
    const float* w = (const float*)d_in[1];   // [64, 4096]  fp32
    float* out = (float*)d_out;

    f16x8* wq  = (f16x8*)d_ws;                        // 1 MB packed B-fragments
    float* lgp = (float*)((char*)d_ws + (1 << 20));   // 4 MB logit partials [2][NTOK][64]

    k0_pack<<<128, 256, 0, stream>>>(w, wq);
    k1_logits<<<1024, 256, 0, stream>>>(h, wq, lgp);
    k2_finish<<<NTOK / 4, 256, 0, stream>>>(lgp, out);
}

// Round 12
// 43.440 us; speedup vs baseline: 1.2138x; 1.2138x over previous
//
#include <hip/hip_runtime.h>
#include <math.h>
#include <stdint.h>

#define NTOK 8192
#define HID  4096
#define NEXP 64
#define TOPK 8

typedef float    f32x4 __attribute__((ext_vector_type(4)));
typedef _Float16 f16x8 __attribute__((ext_vector_type(8)));

// ws layout:
//   [0, 1MB)    : wq — W packed as MFMA B-fragments, f16 hi/lo, x2048 scale.
//                 16B entry index: gs*512 + E*128 + bank*64 + l
//                 (gs = 32-k step 0..127, E = expert-tile 0..3, bank 0=hi 1=lo,
//                  l = lane).  Element: expert e = E*16+(l&15), k = gs*32+(l>>4)*8+j.
//                 k-slice of 16 steps = 128 KB CONTIGUOUS -> linear gll into LDS.
//   [1MB, 17MB) : lgp — logit partials [8][NTOK][64] f32 (x2048 scale)

__device__ __forceinline__ void cvt_hilo(f32x4 a, f32x4 b, f16x8& hi, f16x8& lo)
{
    float x[8] = {a.x, a.y, a.z, a.w, b.x, b.y, b.z, b.w};
#pragma unroll
    for (int j = 0; j < 8; ++j) {
        const _Float16 h = (_Float16)x[j];
        hi[j] = h;
        lo[j] = (_Float16)(x[j] - (float)h);
    }
}

__device__ __forceinline__ void gll16(const void* g, void* l) {
    __builtin_amdgcn_global_load_lds(
        (const __attribute__((address_space(1))) uint32_t*)g,
        (__attribute__((address_space(3))) uint32_t*)l, 16, 0, 0);
}

// ---------------------------------------------------------------------
// k0: W fp32 -> packed B-fragments (x2048). 128 blocks x 256 thr. (proven R11)
// ---------------------------------------------------------------------
__global__ __launch_bounds__(256)
void k0_pack(const float* __restrict__ W, f16x8* __restrict__ wq)
{
    const int gidx = blockIdx.x * 256 + threadIdx.x;   // 0..32767
    const int s = gidx >> 8;            // k-step 0..127
    const int E = (gidx >> 6) & 3;      // expert tile
    const int l = gidx & 63;            // lane
    const int e = E * 16 + (l & 15);
    const int k = s * 32 + ((l >> 4) << 3);

    const float* src = W + (size_t)e * HID + k;
    const f32x4 w0 = *(const f32x4*)src;
    const f32x4 w1 = *(const f32x4*)(src + 4);
    f16x8 hi, lo;
    cvt_hilo(w0 * 2048.0f, w1 * 2048.0f, hi, lo);

    wq[s * 512 + E * 128 + l]      = hi;   // bank 0
    wq[s * 512 + E * 128 + 64 + l] = lo;   // bank 1
}

// ---------------------------------------------------------------------
// k1: partial logits (x2048).  LDS-resident B + ZERO loop barriers.
// grid = 512 (tg = b>>3: 128 tokens; ks = b&7: 512-k slice) x 512 thr (8 waves).
// Block: stage the 128 KB B-slice ONCE (linear gll), one __syncthreads,
// then each wave = 16 tokens x 64 experts x 512 k, 16 fully-unrolled steps:
//   A: 2 f32x4 HBM (depth-4 named ring)   B: 8 ds_read_b128 (conflict-free)
//   12 MFMA (accH + merged-correction accC).  Waves write disjoint lgp slices.
// ---------------------------------------------------------------------
#define ALD(S, GS) do { const float* _p = ha + (GS) * 32;                     \
    A##S##0 = *(const f32x4*)_p; A##S##1 = *(const f32x4*)(_p + 4); } while (0)

#define BLD(S, STEP) do { const _Float16* _q = &BL[(STEP) * 4096];            \
    Bh##S##0 = *(const f16x8*)&_q[           l * 8];                          \
    Bl##S##0 = *(const f16x8*)&_q[ 512 +     l * 8];                          \
    Bh##S##1 = *(const f16x8*)&_q[1024 +     l * 8];                          \
    Bl##S##1 = *(const f16x8*)&_q[1536 +     l * 8];                          \
    Bh##S##2 = *(const f16x8*)&_q[2048 +     l * 8];                          \
    Bl##S##2 = *(const f16x8*)&_q[2560 +     l * 8];                          \
    Bh##S##3 = *(const f16x8*)&_q[3072 +     l * 8];                          \
    Bl##S##3 = *(const f16x8*)&_q[3584 +     l * 8]; } while (0)

#define CSTEP(AS, BS) do { f16x8 _ah, _al; cvt_hilo(A##AS##0, A##AS##1, _ah, _al); \
    acH0 = __builtin_amdgcn_mfma_f32_16x16x32_f16(_ah, Bh##BS##0, acH0, 0, 0, 0); \
    acH1 = __builtin_amdgcn_mfma_f32_16x16x32_f16(_ah, Bh##BS##1, acH1, 0, 0, 0); \
    acH2 = __builtin_amdgcn_mfma_f32_16x16x32_f16(_ah, Bh##BS##2, acH2, 0, 0, 0); \
    acH3 = __builtin_amdgcn_mfma_f32_16x16x32_f16(_ah, Bh##BS##3, acH3, 0, 0, 0); \
    acC0 = __builtin_amdgcn_mfma_f32_16x16x32_f16(_ah, Bl##BS##0, acC0, 0, 0, 0); \
    acC1 = __builtin_amdgcn_mfma_f32_16x16x32_f16(_ah, Bl##BS##1, acC1, 0, 0, 0); \
    acC2 = __builtin_amdgcn_mfma_f32_16x16x32_f16(_ah, Bl##BS##2, acC2, 0, 0, 0); \
    acC3 = __builtin_amdgcn_mfma_f32_16x16x32_f16(_ah, Bl##BS##3, acC3, 0, 0, 0); \
    acC0 = __builtin_amdgcn_mfma_f32_16x16x32_f16(_al, Bh##BS##0, acC0, 0, 0, 0); \
    acC1 = __builtin_amdgcn_mfma_f32_16x16x32_f16(_al, Bh##BS##1, acC1, 0, 0, 0); \
    acC2 = __builtin_amdgcn_mfma_f32_16x16x32_f16(_al, Bh##BS##2, acC2, 0, 0, 0); \
    acC3 = __builtin_amdgcn_mfma_f32_16x16x32_f16(_al, Bh##BS##3, acC3, 0, 0, 0); \
} while (0)

// step S: uses A set (S%4), B set (S%2); refills A for S+4, B for S+2.
#define Q(S, AS, BS) do { CSTEP(AS, BS);                                      \
    if ((S) + 4 < 16) ALD(AS, (S) + 4);                                       \
    if ((S) + 2 < 16) BLD(BS, (S) + 2); } while (0)

__global__ __launch_bounds__(512, 1)
void k1_logits(const float* __restrict__ Hm, const f16x8* __restrict__ wq,
               float* __restrict__ lgp)
{
    __shared__ _Float16 BL[65536];      // 128 KB B-slice image

    const int tid  = threadIdx.x;
    const int w    = tid >> 6;
    const int l    = tid & 63;
    const int tg   = blockIdx.x >> 3;
    const int ks   = blockIdx.x & 7;
    const int tok0 = tg * 128 + w * 16;
    const int kb   = ks * 512;

    // ---- stage B-slice once: 16 linear 8-KB sweeps ----
    const char* wsrc = (const char*)wq + (size_t)ks * 131072;
#pragma unroll
    for (int t = 0; t < 16; ++t)
        gll16(wsrc + t * 8192 + tid * 16, (char*)BL + t * 8192 + tid * 16);
    __syncthreads();

    const float* ha = Hm + (size_t)(tok0 + (l & 15)) * HID + kb + ((l >> 4) << 3);

    f32x4 acH0 = (f32x4)(0.f), acH1 = (f32x4)(0.f), acH2 = (f32x4)(0.f), acH3 = (f32x4)(0.f);
    f32x4 acC0 = (f32x4)(0.f), acC1 = (f32x4)(0.f), acC2 = (f32x4)(0.f), acC3 = (f32x4)(0.f);

    f32x4 Aa0, Aa1, Ab0, Ab1, Ac0, Ac1, Ad0, Ad1;
    f16x8 Bhx0, Bhx1, Bhx2, Bhx3, Blx0, Blx1, Blx2, Blx3;
    f16x8 Bhy0, Bhy1, Bhy2, Bhy3, Bly0, Bly1, Bly2, Bly3;

    ALD(a, 0); ALD(b, 1); ALD(c, 2); ALD(d, 3);
    BLD(x, 0); BLD(y, 1);

    Q( 0, a, x); Q( 1, b, y); Q( 2, c, x); Q( 3, d, y);
    Q( 4, a, x); Q( 5, b, y); Q( 6, c, x); Q( 7, d, y);
    Q( 8, a, x); Q( 9, b, y); Q(10, c, x); Q(11, d, y);
    Q(12, a, x); Q(13, b, y); Q(14, c, x); Q(15, d, y);

    // merge correction bank; C/D: col = l&15 (expert-in-tile), row = (l>>4)*4 + r
    float* o = lgp + ((size_t)ks * NTOK + tok0) * 64;
    {
        const f32x4 v0 = acH0 + acC0, v1 = acH1 + acC1,
                    v2 = acH2 + acC2, v3 = acH3 + acC3;
#pragma unroll
        for (int r = 0; r < 4; ++r) {
            const int trow = ((l >> 4) << 2) + r;
            o[trow * 64 +  0 + (l & 15)] = v0[r];
            o[trow * 64 + 16 + (l & 15)] = v1[r];
            o[trow * 64 + 32 + (l & 15)] = v2[r];
            o[trow * 64 + 48 + (l & 15)] = v3[r];
        }
    }
}

// ---------------------------------------------------------------------
// k2: fixed-order 8-slice reduce + softmax + top-8 rank-count.
// 2048 blocks x 256 thr; 1 token per wave (proven form).
// ---------------------------------------------------------------------
__global__ __launch_bounds__(256)
void k2_finish(const float* __restrict__ lgp, float* __restrict__ out)
{
    __shared__ __align__(16) float sc[4][64];
    const int tid  = threadIdx.x;
    const int wave = tid >> 6;
    const int lane = tid & 63;
    float* outw = out;
    float* outi = out + (size_t)NTOK * TOPK;

    const int tok = blockIdx.x * 4 + wave;
    const float* p = lgp + (size_t)tok * 64 + lane;
    const size_t SL = (size_t)NTOK * 64;
    const float lgv = (((p[0] + p[SL]) + (p[2*SL] + p[3*SL]))
                     + ((p[4*SL] + p[5*SL]) + (p[6*SL] + p[7*SL])))
                     * (1.0f / 2048.0f);

    float mx = lgv;
#pragma unroll
    for (int off = 32; off; off >>= 1) mx = fmaxf(mx, __shfl_xor(mx, off));
    const float pv = expf(lgv - mx);
    float ss = pv;
#pragma unroll
    for (int off = 32; off; off >>= 1) ss += __shfl_xor(ss, off);
    ss = __shfl(ss, 0);                 // identical denominator on all lanes
    const float sval = pv / ss;

    sc[wave][lane] = sval;
    __syncthreads();

    int rank = 0;
#pragma unroll
    for (int j4 = 0; j4 < 16; ++j4) {
        const f32x4 v = *(const f32x4*)&sc[wave][j4 * 4];
#pragma unroll
        for (int u = 0; u < 4; ++u) {
            const int j = j4 * 4 + u;
            rank += (v[u] > sval || (v[u] == sval && j < lane)) ? 1 : 0;
        }
    }
    if (rank < TOPK) {
        outw[(size_t)tok * TOPK + rank] = sval;
        outi[(size_t)tok * TOPK + rank] = (float)lane;
    }
}

extern "C" void kernel_launch(void* const* d_in, const int* in_sizes, int n_in,
                              void* d_out, int out_size, void* d_ws, size_t ws_size,
                              hipStream_t stream) {
    (void)in_sizes; (void)n_in; (void)out_size; (void)ws_size;
    const float* h = (const float*)d_in[0];   // [8192, 4096] fp32
    const float* w = (const float*)d_in[1];   // [64, 4096]  fp32
    float* out = (float*)d_out;

    f16x8* wq  = (f16x8*)d_ws;                        // 1 MB packed B-fragments
    float* lgp = (float*)((char*)d_ws + (1 << 20));   // 16 MB partials [8][NTOK][64]

    k0_pack<<<128, 256, 0, stream>>>(w, wq);
    k1_logits<<<512, 512, 0, stream>>>(h, wq, lgp);
    k2_finish<<<NTOK / 4, 256, 0, stream>>>(lgp, out);
}

// Round 14
// 39.449 us; speedup vs baseline: 1.3366x; 1.1012x over previous
//
#include <hip/hip_runtime.h>
#include <math.h>
#include <stdint.h>

#define NTOK 8192
#define HID  4096
#define NEXP 64
#define TOPK 8

typedef float    f32x4 __attribute__((ext_vector_type(4)));
typedef _Float16 f16x8 __attribute__((ext_vector_type(8)));

// ws layout:
//   [0, 1MB)   : wq — W packed as MFMA B-fragments, f16 hi/lo, x2048 scale.
//                16B entry: gs*512 + E*128 + bank*64 + l  (gs = 32-k step 0..127,
//                E = expert-tile 0..3, bank 0=hi 1=lo, l = lane).
//                Element: expert e = E*16+(l&15), k = gs*32+(l>>4)*8+j.
//                Chunk for one gs = 8 KB contiguous -> linear gll.
//   [1MB, 9MB) : lgp — logit partials [4][NTOK][64] f32 (x2048 scale)

__device__ __forceinline__ void cvt_hilo(f32x4 a, f32x4 b, f16x8& hi, f16x8& lo)
{
    float x[8] = {a.x, a.y, a.z, a.w, b.x, b.y, b.z, b.w};
#pragma unroll
    for (int j = 0; j < 8; ++j) {
        const _Float16 h = (_Float16)x[j];
        hi[j] = h;
        lo[j] = (_Float16)(x[j] - (float)h);
    }
}

__device__ __forceinline__ void gll16(const void* g, void* l) {
    __builtin_amdgcn_global_load_lds(
        (const __attribute__((address_space(1))) uint32_t*)g,
        (__attribute__((address_space(3))) uint32_t*)l, 16, 0, 0);
}

#define MFMA16(AH, BH, AC) \
    AC = __builtin_amdgcn_mfma_f32_16x16x32_f16(AH, BH, AC, 0, 0, 0)

// ---------------------------------------------------------------------
// k0: W fp32 -> packed B-fragments (x2048). 128 blocks x 256 thr. (proven)
// ---------------------------------------------------------------------
__global__ __launch_bounds__(256)
void k0_pack(const float* __restrict__ W, f16x8* __restrict__ wq)
{
    const int gidx = blockIdx.x * 256 + threadIdx.x;   // 0..32767
    const int s = gidx >> 8;            // k-step 0..127
    const int E = (gidx >> 6) & 3;      // expert tile
    const int l = gidx & 63;            // lane
    const int e = E * 16 + (l & 15);
    const int k = s * 32 + ((l >> 4) << 3);

    const float* src = W + (size_t)e * HID + k;
    const f32x4 w0 = *(const f32x4*)src;
    const f32x4 w1 = *(const f32x4*)(src + 4);
    f16x8 hi, lo;
    cvt_hilo(w0 * 2048.0f, w1 * 2048.0f, hi, lo);

    wq[s * 512 + E * 128 + l]      = hi;   // bank 0
    wq[s * 512 + E * 128 + 64 + l] = lo;   // bank 1
}

// ---------------------------------------------------------------------
// k1: partial logits (x2048).  COALESCED-A via LDS stream-chunks.
// grid = 512 blocks (tokgrp = b>>2: 64 tokens; ksb = b&3: 1024-k slice)
// x 512 thr (8 waves = 4 tok-groups x 2 exp-groups).  QUAD-buffered A+B
// 8-KB chunks staged 2 steps ahead via gll.  Sync per step (m201 order):
//   STAGE(S+2) -> vmcnt(N) [drains own tile-S glls] -> s_barrier
//   [all waves' tile-S writes now complete] -> ds_read/cvt/6 MFMA.
// Slot (S+2)%4's prior readers (step S-2) are 2 barriers back: overwrite-safe.
// A-tile: [t(64)][granule o(8)] 16B granules, source-swizzled o^=(t&7)
// -> ds_read conflict-free; gll source = 8 rows x 128 B per instr.
// ---------------------------------------------------------------------
#define STAGE2(S) do {                                                        \
    gll16(hap + (size_t)(S) * 128,  &LDSB[((S) % 4) * 8192 + tid * 16]);      \
    gll16(bap + (size_t)(S) * 8192, &LDSB[32768 + ((S) % 4) * 8192 + tid * 16]); \
} while (0)

#define KSTEP(S, VN) do {                                                     \
    if ((S) + 2 < 32) STAGE2((S) + 2);                                        \
    asm volatile("s_waitcnt vmcnt(" #VN ")" ::: "memory");                    \
    __builtin_amdgcn_sched_barrier(0);                                        \
    __builtin_amdgcn_s_barrier();                                             \
    __builtin_amdgcn_sched_barrier(0);                                        \
    const char* _A = &LDSB[((S) % 4) * 8192];                                 \
    const char* _B = &LDSB[32768 + ((S) % 4) * 8192];                         \
    const f32x4 a0 = *(const f32x4*)&_A[ga0 * 16];                            \
    const f32x4 a1 = *(const f32x4*)&_A[ga1 * 16];                            \
    const f16x8 bh0 = *(const f16x8*)&_B[(E0 * 128 + l) * 16];                \
    const f16x8 bl0 = *(const f16x8*)&_B[(E0 * 128 + 64 + l) * 16];           \
    const f16x8 bh1 = *(const f16x8*)&_B[(E1 * 128 + l) * 16];                \
    const f16x8 bl1 = *(const f16x8*)&_B[(E1 * 128 + 64 + l) * 16];           \
    f16x8 _ah, _al; cvt_hilo(a0, a1, _ah, _al);                               \
    MFMA16(_ah, bh0, acH0); MFMA16(_ah, bh1, acH1);                           \
    MFMA16(_ah, bl0, acC0); MFMA16(_ah, bl1, acC1);                           \
    MFMA16(_al, bh0, acC0); MFMA16(_al, bh1, acC1);                           \
} while (0)

__global__ __launch_bounds__(512, 2)
void k1_logits(const float* __restrict__ Hm, const char* __restrict__ wqc,
               float* __restrict__ lgp)
{
    __shared__ char LDSB[65536];        // A: 4x8KB @0, B: 4x8KB @32768

    const int tid  = threadIdx.x;
    const int wave = tid >> 6;
    const int l    = tid & 63;
    const int kg   = l >> 4;
    const int tg   = wave >> 1;         // token group 0..3 (16 tokens)
    const int eg   = wave & 1;          // expert group 0..1 (32 experts)
    const int E0   = eg * 2;
    const int E1   = eg * 2 + 1;
    const int tokg = blockIdx.x >> 2;
    const int ksb  = blockIdx.x & 3;
    const int tok0 = tokg * 64;
    const int kb   = ksb * 1024;

    // A-frag read granules (step-invariant): t_loc = tg*16+(l&15), c = kg*2+j
    const int tloc = tg * 16 + (l & 15);
    const int ga0  = tloc * 8 + ((kg * 2)     ^ (l & 7));
    const int ga1  = tloc * 8 + ((kg * 2 + 1) ^ (l & 7));

    // staging identities: thread stages granule (t = tid>>3, o = tid&7),
    // source chunk c = o ^ (t&7) -> 8 rows x 128 B contiguous per gll.
    const int st = tid >> 3;
    const int so = tid & 7;
    const char* hap = (const char*)(Hm + (size_t)(tok0 + st) * HID + kb)
                    + ((so ^ (st & 7)) * 16);
    const char* bap = wqc + (size_t)ksb * 262144 + tid * 16;

    f32x4 acH0 = (f32x4)(0.f), acH1 = (f32x4)(0.f);
    f32x4 acC0 = (f32x4)(0.f), acC1 = (f32x4)(0.f);

    STAGE2(0); STAGE2(1);

    KSTEP( 0, 4); KSTEP( 1, 4); KSTEP( 2, 4); KSTEP( 3, 4);
    KSTEP( 4, 4); KSTEP( 5, 4); KSTEP( 6, 4); KSTEP( 7, 4);
    KSTEP( 8, 4); KSTEP( 9, 4); KSTEP(10, 4); KSTEP(11, 4);
    KSTEP(12, 4); KSTEP(13, 4); KSTEP(14, 4); KSTEP(15, 4);
    KSTEP(16, 4); KSTEP(17, 4); KSTEP(18, 4); KSTEP(19, 4);
    KSTEP(20, 4); KSTEP(21, 4); KSTEP(22, 4); KSTEP(23, 4);
    KSTEP(24, 4); KSTEP(25, 4); KSTEP(26, 4); KSTEP(27, 4);
    KSTEP(28, 4); KSTEP(29, 4); KSTEP(30, 2); KSTEP(31, 0);

    // C/D: col = l&15 (expert-in-tile), row = (l>>4)*4 + r (token-in-tile)
    const f32x4 v0 = acH0 + acC0;
    const f32x4 v1 = acH1 + acC1;
    float* o = lgp + ((size_t)ksb * NTOK + tok0 + tg * 16) * 64 + eg * 32;
#pragma unroll
    for (int r = 0; r < 4; ++r) {
        const int row = (kg << 2) + r;
        o[row * 64 +      (l & 15)] = v0[r];
        o[row * 64 + 16 + (l & 15)] = v1[r];
    }
}

// ---------------------------------------------------------------------
// k2: fixed-order 4-slice reduce + softmax + top-8 rank-count.
// 2048 blocks x 256 thr; 1 token per wave (proven form).
// ---------------------------------------------------------------------
__global__ __launch_bounds__(256)
void k2_finish(const float* __restrict__ lgp, float* __restrict__ out)
{
    __shared__ __align__(16) float sc[4][64];
    const int tid  = threadIdx.x;
    const int wave = tid >> 6;
    const int lane = tid & 63;
    float* outw = out;
    float* outi = out + (size_t)NTOK * TOPK;

    const int tok = blockIdx.x * 4 + wave;
    const float* p = lgp + (size_t)tok * 64 + lane;
    const size_t SL = (size_t)NTOK * 64;
    const float lgv = ((p[0] + p[SL]) + (p[2 * SL] + p[3 * SL])) * (1.0f / 2048.0f);

    float mx = lgv;
#pragma unroll
    for (int off = 32; off; off >>= 1) mx = fmaxf(mx, __shfl_xor(mx, off));
    const float pv = expf(lgv - mx);
    float ss = pv;
#pragma unroll
    for (int off = 32; off; off >>= 1) ss += __shfl_xor(ss, off);
    ss = __shfl(ss, 0);                 // identical denominator on all lanes
    const float sval = pv / ss;

    sc[wave][lane] = sval;
    __syncthreads();

    int rank = 0;
#pragma unroll
    for (int j4 = 0; j4 < 16; ++j4) {
        const f32x4 v = *(const f32x4*)&sc[wave][j4 * 4];
#pragma unroll
        for (int u = 0; u < 4; ++u) {
            const int j = j4 * 4 + u;
            rank += (v[u] > sval || (v[u] == sval && j < lane)) ? 1 : 0;
        }
    }
    if (rank < TOPK) {
        outw[(size_t)tok * TOPK + rank] = sval;
        outi[(size_t)tok * TOPK + rank] = (float)lane;
    }
}

extern "C" void kernel_launch(void* const* d_in, const int* in_sizes, int n_in,
                              void* d_out, int out_size, void* d_ws, size_t ws_size,
                              hipStream_t stream) {
    (void)in_sizes; (void)n_in; (void)out_size; (void)ws_size;
    const float* h = (const float*)d_in[0];   // [8192, 4096] fp32
    const float* w = (const float*)d_in[1];   // [64, 4096]  fp32
    float* out = (float*)d_out;

    f16x8* wq  = (f16x8*)d_ws;                        // 1 MB packed B-fragments
    float* lgp = (float*)((char*)d_ws + (1 << 20));   // 8 MB partials [4][NTOK][64]

    k0_pack<<<128, 256, 0, stream>>>(w, wq);
    k1_logits<<<512, 512, 0, stream>>>(h, (const char*)wq, lgp);
    k2_finish<<<NTOK / 4, 256, 0, stream>>>(lgp, out);
}